// Round 2
// baseline (1091.411 us; speedup 1.0000x reference)
//
#include <hip/hip_runtime.h>
#include <hip/hip_cooperative_groups.h>
#include <cstdint>
#include <cstddef>

namespace cg = cooperative_groups;

// Problem constants
#define B_    64
#define H_    8
#define N_    16384
#define M_    64
#define C_    1024
#define IVH_  198          // 3*M+6
#define J_    1584         // H*IVH
#define NCHUNK_ 64         // N/256

__device__ __forceinline__ float softplus_f(float x) {
    return (x > 20.f) ? x : log1pf(__expf(x));
}
__device__ __forceinline__ float sigmoid_f(float x) {
    return 1.f / (1.f + __expf(-x));
}
// branchless 8-way select (cndmask chain; no scratch)
__device__ __forceinline__ float sel8(const float p[8], int i) {
    float r01 = (i & 1) ? p[1] : p[0];
    float r23 = (i & 1) ? p[3] : p[2];
    float r45 = (i & 1) ? p[5] : p[4];
    float r67 = (i & 1) ? p[7] : p[6];
    float a = (i & 2) ? r23 : r01;
    float c = (i & 2) ? r67 : r45;
    return (i & 4) ? c : a;
}

// ---------------------------------------------------------------------------
// Kernel 1: iv = x @ W (no bias; consumers add it). Proven round-0 config:
// grid (25, 4, 8), block 64, 128-c chunks, atomic accumulate.
__global__ __launch_bounds__(64) void k_gemm(const float* __restrict__ x,
                                             const float* __restrict__ W,
                                             float* __restrict__ iv) {
    int lane = threadIdx.x;
    int j = blockIdx.x * 64 + lane;
    bool valid = (j < J_);
    int b0 = blockIdx.y * 16;
    int c0 = blockIdx.z * 128;
    const float* xb = x + (size_t)b0 * C_;
    float acc[16];
    #pragma unroll
    for (int i = 0; i < 16; ++i) acc[i] = 0.f;
    #pragma unroll 2
    for (int c = c0; c < c0 + 128; ++c) {
        float wv = valid ? W[(size_t)c * J_ + j] : 0.f;
        #pragma unroll
        for (int bi = 0; bi < 16; ++bi)
            acc[bi] = fmaf(xb[(size_t)bi * C_ + c], wv, acc[bi]);
    }
    if (valid) {
        #pragma unroll
        for (int bi = 0; bi < 16; ++bi)
            atomicAdd(&iv[(size_t)(b0 + bi) * J_ + j], acc[bi]);
    }
}

// ---------------------------------------------------------------------------
// Shared LDS layout (floats):
//   [0..3071]    wp_s (phase B, stride 12)  /  zl (phase A, [h*264+row], 2112)
//   [3072..5135] wgl (phase B, [h*258+i])   /  racc2 (2048, overlays)
//   [5136..5167] sums
//   [5168..5231] pl  (per-(b,h) params: Mx,iS,g,s0,s1,s2,gam)
#define SMEM_FLOATS 5232

// ---- phase A: z = beta*cos for 4 chunks; chunk softmax partials ----
__device__ __forceinline__ void phaseA_body(
        int b, int ci0, int t, float* smem,
        const float* __restrict__ mem, const float* __restrict__ iv,
        const float* __restrict__ bias, float* __restrict__ z,
        float* __restrict__ pmax, float* __restrict__ psum) {
    float* zl = smem;
    int w = t >> 6, lane = t & 63;
    int sub8 = lane >> 3, mq8 = lane & 7;

    // k prep: 8 m's per lane per h; 3-stage shuffle reduce for ||k||^2
    const float* ivb = iv + (size_t)b * J_;
    float4 ka[8], kb[8];
    float kn[8];
    #pragma unroll
    for (int h = 0; h < 8; ++h) {
        const float* ivh = ivb + h * IVH_ + mq8 * 8;
        const float* bbh = bias + h * IVH_ + mq8 * 8;
        float e0 = ivh[0]+bbh[0], e1 = ivh[1]+bbh[1], e2 = ivh[2]+bbh[2], e3 = ivh[3]+bbh[3];
        float e4 = ivh[4]+bbh[4], e5 = ivh[5]+bbh[5], e6 = ivh[6]+bbh[6], e7 = ivh[7]+bbh[7];
        float q = e0*e0+e1*e1+e2*e2+e3*e3+e4*e4+e5*e5+e6*e6+e7*e7;
        q += __shfl_xor(q, 1, 64);
        q += __shfl_xor(q, 2, 64);
        q += __shfl_xor(q, 4, 64);
        kn[h] = sqrtf(q);
        float v0 = ivb[h * IVH_ + 64] + bias[h * IVH_ + 64];
        float s = softplus_f(v0) / kn[h];          // beta / ||k||
        ka[h] = make_float4(e0*s, e1*s, e2*s, e3*s);
        kb[h] = make_float4(e4*s, e5*s, e6*s, e7*s);
    }
    // beta*dot/(kn*rn+1e-16) == (beta/kn)*dot/(rn + 1e-16/kn)
    float epsl = 1e-16f / sel8(kn, mq8);

    #pragma unroll 1
    for (int kc = 0; kc < 4; ++kc) {
        int ck = ci0 * 4 + kc;
        int n0 = ck << 8;
        const float* mb = mem + ((size_t)b * N_ + n0) * M_;
        #pragma unroll
        for (int rr = 0; rr < 8; ++rr) {
            int row = (w << 6) + (rr << 3) + sub8;
            const float* mr = mb + (size_t)row * M_ + mq8 * 8;
            float4 m0 = *(const float4*)(mr);
            float4 m1 = *(const float4*)(mr + 4);
            float pr[9];
            #pragma unroll
            for (int h = 0; h < 8; ++h)
                pr[h] = ka[h].x*m0.x + ka[h].y*m0.y + ka[h].z*m0.z + ka[h].w*m0.w
                      + kb[h].x*m1.x + kb[h].y*m1.y + kb[h].z*m1.z + kb[h].w*m1.w;
            pr[8] = m0.x*m0.x+m0.y*m0.y+m0.z*m0.z+m0.w*m0.w
                  + m1.x*m1.x+m1.y*m1.y+m1.z*m1.z+m1.w*m1.w;
            #pragma unroll
            for (int o = 1; o < 8; o <<= 1) {
                #pragma unroll
                for (int i = 0; i < 9; ++i) pr[i] += __shfl_xor(pr[i], o, 64);
            }
            float rn = sqrtf(pr[8]);
            zl[mq8 * 264 + row] = sel8(pr, mq8) / (rn + epsl);
        }
        __syncthreads();
        // z store (coalesced per h)
        #pragma unroll
        for (int h = 0; h < 8; ++h)
            z[(((size_t)b * 8 + h) << 14) + n0 + t] = zl[h * 264 + t];
        // chunk softmax partials: wave w handles h = 2w, 2w+1
        #pragma unroll
        for (int q2 = 0; q2 < 2; ++q2) {
            int h = w * 2 + q2;
            float a0 = zl[h * 264 + lane],       a1 = zl[h * 264 + lane + 64];
            float a2 = zl[h * 264 + lane + 128], a3 = zl[h * 264 + lane + 192];
            float mx = fmaxf(fmaxf(a0, a1), fmaxf(a2, a3));
            #pragma unroll
            for (int o = 32; o > 0; o >>= 1) mx = fmaxf(mx, __shfl_xor(mx, o, 64));
            float se = __expf(a0 - mx) + __expf(a1 - mx) + __expf(a2 - mx) + __expf(a3 - mx);
            #pragma unroll
            for (int o = 32; o > 0; o >>= 1) se += __shfl_xor(se, o, 64);
            if (lane == 0) {
                pmax[(((size_t)b * 8 + h) << 6) + ck] = mx;
                psum[(((size_t)b * 8 + h) << 6) + ck] = se;
            }
        }
        __syncthreads();
    }
}

// ---- phase S: global softmax stats + g/s/gamma -> pl ----
__device__ __forceinline__ void phaseS_body(
        int b, int t, float* pl,
        const float* __restrict__ pmax, const float* __restrict__ psum,
        const float* __restrict__ iv, const float* __restrict__ bias) {
    int w = t >> 6, lane = t & 63;
    #pragma unroll
    for (int q2 = 0; q2 < 2; ++q2) {
        int h = w * 2 + q2;
        size_t bh = (size_t)b * 8 + h;
        float m = pmax[(bh << 6) + lane];
        float s = psum[(bh << 6) + lane];
        float mx = m;
        #pragma unroll
        for (int o = 32; o > 0; o >>= 1) mx = fmaxf(mx, __shfl_xor(mx, o, 64));
        float sc = s * __expf(m - mx);
        #pragma unroll
        for (int o = 32; o > 0; o >>= 1) sc += __shfl_xor(sc, o, 64);
        if (lane == 0) { pl[h * 8 + 0] = mx; pl[h * 8 + 1] = 1.f / sc; }
    }
    if (t < 8) {
        const float* ivh = iv + (size_t)b * J_ + t * IVH_;
        const float* bbh = bias + t * IVH_;
        float v1 = ivh[65] + bbh[65];
        float v2 = ivh[66] + bbh[66];
        float v3 = ivh[67] + bbh[67];
        float v4 = ivh[68] + bbh[68];
        float v5 = ivh[69] + bbh[69];
        float mx3 = fmaxf(v2, fmaxf(v3, v4));
        float e2 = __expf(v2 - mx3), e3 = __expf(v3 - mx3), e4 = __expf(v4 - mx3);
        float inv = 1.f / (e2 + e3 + e4);
        pl[t * 8 + 2] = sigmoid_f(v1);
        pl[t * 8 + 3] = e2 * inv;
        pl[t * 8 + 4] = e3 * inv;
        pl[t * 8 + 5] = e4 * inv;
        pl[t * 8 + 6] = 1.f + softplus_f(v5);
    }
    __syncthreads();
}

// ---- phase B: wg->ws->wp (out_w unnormalized), sumwp + readAcc partials ----
__device__ __forceinline__ void phaseB_body(
        int b, int ci0, int t, float* smem, const float* pl,
        const float* __restrict__ mem, const float* __restrict__ z,
        const float* __restrict__ wprev, float* __restrict__ out_w,
        float* __restrict__ sumwp, float* __restrict__ readAcc) {
    float* wp_s  = smem;
    float* wgl   = smem + 3072;
    float* racc2 = smem + 3072;
    float* sums  = smem + 5136;
    int w = t >> 6, lane = t & 63, sub = lane >> 4, mq = lane & 15;

    float4 acc[8];
    #pragma unroll
    for (int h = 0; h < 8; ++h) acc[h] = make_float4(0.f, 0.f, 0.f, 0.f);
    float ssum[8] = {0.f,0.f,0.f,0.f,0.f,0.f,0.f,0.f};

    #pragma unroll 1
    for (int kc = 0; kc < 4; ++kc) {
        int ck = ci0 * 4 + kc;
        int n0 = ck << 8;
        int n = n0 + t;
        #pragma unroll
        for (int h = 0; h < 8; ++h) {
            size_t bh = (size_t)b * 8 + h;
            float Mx = pl[h * 8 + 0], iS = pl[h * 8 + 1], g = pl[h * 8 + 2];
            float wc = __expf(z[(bh << 14) + n] - Mx) * iS;
            wgl[h * 258 + t + 1] = fmaf(g, wc, (1.f - g) * wprev[(bh << 14) + n]);
        }
        if (t < 2) {
            int nh   = (t == 0) ? ((n0 + N_ - 1) & (N_ - 1)) : ((n0 + 256) & (N_ - 1));
            int slot = (t == 0) ? 0 : 257;
            #pragma unroll
            for (int h = 0; h < 8; ++h) {
                size_t bh = (size_t)b * 8 + h;
                float Mx = pl[h * 8 + 0], iS = pl[h * 8 + 1], g = pl[h * 8 + 2];
                float wc = __expf(z[(bh << 14) + nh] - Mx) * iS;
                wgl[h * 258 + slot] = fmaf(g, wc, (1.f - g) * wprev[(bh << 14) + nh]);
            }
        }
        __syncthreads();
        float wpv[8];
        #pragma unroll
        for (int h = 0; h < 8; ++h) {
            size_t bh = (size_t)b * 8 + h;
            float s0 = pl[h * 8 + 3], s1 = pl[h * 8 + 4], s2 = pl[h * 8 + 5];
            float gam = pl[h * 8 + 6];
            float wsv = s0 * wgl[h * 258 + t] + s1 * wgl[h * 258 + t + 1]
                      + s2 * wgl[h * 258 + t + 2];
            float v = __powf(wsv, gam);
            wpv[h] = v;
            ssum[h] += v;
            out_w[(bh << 14) + n] = v;          // unnormalized; phase F rescales
        }
        *(float4*)(wp_s + t * 12)     = make_float4(wpv[0], wpv[1], wpv[2], wpv[3]);
        *(float4*)(wp_s + t * 12 + 4) = make_float4(wpv[4], wpv[5], wpv[6], wpv[7]);
        __syncthreads();
        const float* mb = mem + ((size_t)b * N_ + n0) * M_;
        #pragma unroll
        for (int rr = 0; rr < 16; ++rr) {
            int row = (w << 6) + (rr << 2) + sub;
            float4 mv = *(const float4*)(mb + (size_t)row * M_ + mq * 4);
            float4 wA = *(const float4*)(wp_s + row * 12);
            float4 wB = *(const float4*)(wp_s + row * 12 + 4);
            float wv8[8] = {wA.x, wA.y, wA.z, wA.w, wB.x, wB.y, wB.z, wB.w};
            #pragma unroll
            for (int h = 0; h < 8; ++h) {
                acc[h].x = fmaf(wv8[h], mv.x, acc[h].x);
                acc[h].y = fmaf(wv8[h], mv.y, acc[h].y);
                acc[h].z = fmaf(wv8[h], mv.z, acc[h].z);
                acc[h].w = fmaf(wv8[h], mv.w, acc[h].w);
            }
        }
        __syncthreads();
    }

    // sumwp partial (one atomic per (b,h) per block)
    #pragma unroll
    for (int h = 0; h < 8; ++h) {
        float s = ssum[h];
        #pragma unroll
        for (int o = 32; o > 0; o >>= 1) s += __shfl_down(s, o, 64);
        if (lane == 0) sums[w * 8 + h] = s;
    }
    // readAcc partial (accumulated over the 4 chunks already)
    #pragma unroll
    for (int h = 0; h < 8; ++h) {
        #pragma unroll
        for (int o = 32; o >= 16; o >>= 1) {
            acc[h].x += __shfl_down(acc[h].x, o, 64);
            acc[h].y += __shfl_down(acc[h].y, o, 64);
            acc[h].z += __shfl_down(acc[h].z, o, 64);
            acc[h].w += __shfl_down(acc[h].w, o, 64);
        }
    }
    if (lane < 16) {
        #pragma unroll
        for (int h = 0; h < 8; ++h)
            *(float4*)(racc2 + ((w * 8 + h) << 6) + mq * 4) = acc[h];
    }
    __syncthreads();
    if (t < 8)
        atomicAdd(&sumwp[b * 8 + t], sums[t] + sums[8 + t] + sums[16 + t] + sums[24 + t]);
    #pragma unroll
    for (int r = 0; r < 2; ++r) {
        int idx = r * 256 + t;
        float s = racc2[idx] + racc2[512 + idx] + racc2[1024 + idx] + racc2[1536 + idx];
        atomicAdd(&readAcc[(size_t)b * 512 + idx], s);
    }
}

// ---- phase F: normalize out_w; read_data / e / a epilogue ----
__device__ __forceinline__ void phaseF_body(
        int b, int ci0, int t, float* pl,
        float* __restrict__ out_w, const float* __restrict__ sumwp,
        const float* __restrict__ readAcc, const float* __restrict__ iv,
        const float* __restrict__ bias, float* __restrict__ out_rd,
        float* __restrict__ out_e, float* __restrict__ out_a) {
    if (t < 8) pl[t] = 1.f / (sumwp[b * 8 + t] + 1e-16f);
    __syncthreads();
    #pragma unroll 1
    for (int kc = 0; kc < 4; ++kc) {
        int n0 = (ci0 * 4 + kc) << 8;
        #pragma unroll
        for (int h = 0; h < 8; ++h) {
            size_t idx = (((size_t)b * 8 + h) << 14) + n0 + t;
            out_w[idx] *= pl[h];
        }
    }
    if (ci0 == 0) {
        #pragma unroll
        for (int r = 0; r < 2; ++r) {
            int i = r * 256 + t;
            int gi = b * 512 + i;
            out_rd[gi] = readAcc[gi] * pl[i >> 6];
            int h = i >> 6, m = i & 63;
            int offe = h * IVH_ + 70 + m;              // M+6
            out_e[gi] = sigmoid_f(iv[(size_t)b * J_ + offe] + bias[offe]);
            int offa = h * IVH_ + 134 + m;             // 2M+6
            out_a[gi] = iv[(size_t)b * J_ + offa] + bias[offa];
        }
    }
}

// ---------------------------------------------------------------------------
// Fused cooperative kernel: grid 1024 x 256; block g -> b=g>>4, ci0=g&15,
// chunks ci0*4 .. ci0*4+3. Two grid syncs replace three kernel boundaries.
__global__ __launch_bounds__(256, 4) void k_fused(
        const float* __restrict__ mem, const float* __restrict__ wprev,
        const float* __restrict__ iv, const float* __restrict__ bias,
        float* __restrict__ z, float* __restrict__ pmax, float* __restrict__ psum,
        float* __restrict__ out_w, float* __restrict__ sumwp,
        float* __restrict__ readAcc, float* __restrict__ out_rd,
        float* __restrict__ out_e, float* __restrict__ out_a) {
    __shared__ float smem[SMEM_FLOATS];
    float* pl = smem + 5168;
    cg::grid_group grid = cg::this_grid();

    int t = threadIdx.x;
    int b   = (int)(blockIdx.x >> 4);
    int ci0 = (int)(blockIdx.x & 15);

    phaseA_body(b, ci0, t, smem, mem, iv, bias, z, pmax, psum);
    __threadfence();
    grid.sync();
    phaseS_body(b, t, pl, pmax, psum, iv, bias);
    phaseB_body(b, ci0, t, smem, pl, mem, z, wprev, out_w, sumwp, readAcc);
    __threadfence();
    grid.sync();
    phaseF_body(b, ci0, t, pl, out_w, sumwp, readAcc, iv, bias, out_rd, out_e, out_a);
}

// ---- fallback (non-cooperative) kernels: same bodies, 3 launches ----
__global__ __launch_bounds__(256, 4) void k_A(
        const float* __restrict__ mem, const float* __restrict__ iv,
        const float* __restrict__ bias, float* __restrict__ z,
        float* __restrict__ pmax, float* __restrict__ psum) {
    __shared__ float smem[SMEM_FLOATS];
    int t = threadIdx.x;
    phaseA_body((int)(blockIdx.x >> 4), (int)(blockIdx.x & 15), t, smem,
                mem, iv, bias, z, pmax, psum);
}
__global__ __launch_bounds__(256, 4) void k_B(
        const float* __restrict__ mem, const float* __restrict__ wprev,
        const float* __restrict__ iv, const float* __restrict__ bias,
        const float* __restrict__ z, const float* __restrict__ pmax,
        const float* __restrict__ psum, float* __restrict__ out_w,
        float* __restrict__ sumwp, float* __restrict__ readAcc) {
    __shared__ float smem[SMEM_FLOATS];
    float* pl = smem + 5168;
    int t = threadIdx.x;
    int b = (int)(blockIdx.x >> 4), ci0 = (int)(blockIdx.x & 15);
    phaseS_body(b, t, pl, pmax, psum, iv, bias);
    phaseB_body(b, ci0, t, smem, pl, mem, z, wprev, out_w, sumwp, readAcc);
}
__global__ __launch_bounds__(256, 4) void k_F(
        float* __restrict__ out_w, const float* __restrict__ sumwp,
        const float* __restrict__ readAcc, const float* __restrict__ iv,
        const float* __restrict__ bias, float* __restrict__ out_rd,
        float* __restrict__ out_e, float* __restrict__ out_a) {
    __shared__ float smem[SMEM_FLOATS];
    float* pl = smem + 5168;
    int t = threadIdx.x;
    phaseF_body((int)(blockIdx.x >> 4), (int)(blockIdx.x & 15), t, pl,
                out_w, sumwp, readAcc, iv, bias, out_rd, out_e, out_a);
}

// ---------------------------------------------------------------------------
extern "C" void kernel_launch(void* const* d_in, const int* in_sizes, int n_in,
                              void* d_out, int out_size, void* d_ws, size_t ws_size,
                              hipStream_t stream) {
    const float* x     = (const float*)d_in[0];
    const float* mem   = (const float*)d_in[1];
    const float* wprev = (const float*)d_in[2];
    const float* W     = (const float*)d_in[3];
    const float* bias  = (const float*)d_in[4];

    float* out    = (float*)d_out;
    float* out_rd = out;                         // 32768
    float* out_w  = out + 32768;                 // 8388608
    float* out_e  = out + 32768 + 8388608;       // 32768
    float* out_a  = out_e + 32768;               // 32768

    float* ws      = (float*)d_ws;
    float* iv      = ws;                  // 101376  (zeroed)
    float* sumwp   = iv + 101376;         // 512     (zeroed)
    float* readAcc = sumwp + 512;         // 32768   (zeroed)
    float* zbuf    = readAcc + 32768;     // 8388608
    float* pmax    = zbuf + 8388608;      // 32768
    float* psum    = pmax + 32768;        // 32768

    hipMemsetAsync(iv, 0, (size_t)(101376 + 512 + 32768) * 4, stream);

    k_gemm<<<dim3(25, 4, 8), 64, 0, stream>>>(x, W, iv);

    void* args[] = {(void*)&mem, (void*)&wprev, (void*)&iv, (void*)&bias,
                    (void*)&zbuf, (void*)&pmax, (void*)&psum, (void*)&out_w,
                    (void*)&sumwp, (void*)&readAcc, (void*)&out_rd,
                    (void*)&out_e, (void*)&out_a};
    hipError_t err = hipLaunchCooperativeKernel((void*)k_fused, dim3(1024), dim3(256),
                                                args, 0, stream);
    if (err != hipSuccess) {
        // fallback: same phases as ordinary kernels
        k_A<<<1024, 256, 0, stream>>>(mem, iv, bias, zbuf, pmax, psum);
        k_B<<<1024, 256, 0, stream>>>(mem, wprev, iv, bias, zbuf, pmax, psum,
                                      out_w, sumwp, readAcc);
        k_F<<<1024, 256, 0, stream>>>(out_w, sumwp, readAcc, iv, bias,
                                      out_rd, out_e, out_a);
    }
}

// Round 3
// 543.471 us; speedup vs baseline: 2.0082x; 2.0082x over previous
//
#include <hip/hip_runtime.h>
#include <cstdint>
#include <cstddef>

// Problem constants
#define B_    64
#define H_    8
#define N_    16384
#define M_    64
#define C_    1024
#define IVH_  198          // 3*M+6
#define J_    1584         // H*IVH
#define NCHUNK_ 64         // N/256

__device__ __forceinline__ float softplus_f(float x) {
    return (x > 20.f) ? x : log1pf(__expf(x));
}
__device__ __forceinline__ float sigmoid_f(float x) {
    return 1.f / (1.f + __expf(-x));
}
// branchless 8-way select (cndmask chain; no scratch)
__device__ __forceinline__ float sel8(const float p[8], int i) {
    float r01 = (i & 1) ? p[1] : p[0];
    float r23 = (i & 1) ? p[3] : p[2];
    float r45 = (i & 1) ? p[5] : p[4];
    float r67 = (i & 1) ? p[7] : p[6];
    float a = (i & 2) ? r23 : r01;
    float c = (i & 2) ? r67 : r45;
    return (i & 4) ? c : a;
}

// ---------------------------------------------------------------------------
// Kernel 1: iv = x @ W (no bias; consumers add it). Round-0-proven config:
// grid (25, 4, 8), block 64, 128-c chunks, atomic accumulate.
__global__ __launch_bounds__(64) void k_gemm(const float* __restrict__ x,
                                             const float* __restrict__ W,
                                             float* __restrict__ iv) {
    int lane = threadIdx.x;
    int j = blockIdx.x * 64 + lane;
    bool valid = (j < J_);
    int b0 = blockIdx.y * 16;
    int c0 = blockIdx.z * 128;
    const float* xb = x + (size_t)b0 * C_;
    float acc[16];
    #pragma unroll
    for (int i = 0; i < 16; ++i) acc[i] = 0.f;
    #pragma unroll 2
    for (int c = c0; c < c0 + 128; ++c) {
        float wv = valid ? W[(size_t)c * J_ + j] : 0.f;
        #pragma unroll
        for (int bi = 0; bi < 16; ++bi)
            acc[bi] = fmaf(xb[(size_t)bi * C_ + c], wv, acc[bi]);
    }
    if (valid) {
        #pragma unroll
        for (int bi = 0; bi < 16; ++bi)
            atomicAdd(&iv[(size_t)(b0 + bi) * J_ + j], acc[bi]);
    }
}

// ---------------------------------------------------------------------------
// Kernel 2: per-(b,h) parameter extraction. grid 512 blocks, block 64.
// Emits k pre-scaled by beta/||k||, P = {eps/||k||, g, s0,s1,s2, gamma},
// and the e/a output epilogue (removed from the final pass).
__global__ void k_params(const float* __restrict__ iv, const float* __restrict__ bias,
                         float* __restrict__ kbuf, float* __restrict__ P,
                         float* __restrict__ out_e, float* __restrict__ out_a) {
    int bh = blockIdx.x;
    int m  = threadIdx.x;              // 0..63
    int b = bh >> 3, h = bh & 7;
    const float* row = iv + (size_t)b * J_ + h * IVH_;
    const float* bb  = bias + h * IVH_;
    float kv = row[m] + bb[m];
    float s = kv * kv;
    #pragma unroll
    for (int o = 32; o > 0; o >>= 1) s += __shfl_xor(s, o, 64);
    float kn = sqrtf(s);
    float beta = softplus_f(row[64] + bb[64]);     // wave-uniform loads
    kbuf[(size_t)bh * 64 + m] = kv * (beta / kn);  // beta/||k|| folded into k
    float ev = row[70 + m] + bb[70 + m];           // M+6 = 70
    out_e[(size_t)bh * 64 + m] = sigmoid_f(ev);
    out_a[(size_t)bh * 64 + m] = row[134 + m] + bb[134 + m];  // 2M+6 = 134
    if (m == 0) {
        float v1 = row[65] + bb[65];
        float v2 = row[66] + bb[66];
        float v3 = row[67] + bb[67];
        float v4 = row[68] + bb[68];
        float v5 = row[69] + bb[69];
        float mx3 = fmaxf(v2, fmaxf(v3, v4));
        float e2 = __expf(v2 - mx3), e3 = __expf(v3 - mx3), e4 = __expf(v4 - mx3);
        float inv = 1.f / (e2 + e3 + e4);
        float* p = P + (size_t)bh * 8;
        p[0] = 1e-16f / kn;            // eps local: beta*dot/(kn*rn+eps) == khat.dot/(rn+eps/kn)
        p[1] = sigmoid_f(v1);          // g
        p[2] = e2 * inv; p[3] = e3 * inv; p[4] = e4 * inv;  // s0,s1,s2
        p[5] = 1.f + softplus_f(v5);   // gamma
    }
}

// ---------------------------------------------------------------------------
// Kernel 3 (pass A): z = scaled cos for one 256-row chunk; chunk softmax
// partials. 8 lanes per row, 3-stage xor reduce. grid (64, 64), block 256.
__global__ __launch_bounds__(256, 4) void k_A(
        const float* __restrict__ mem, const float* __restrict__ kbuf,
        const float* __restrict__ P, float* __restrict__ z,
        float* __restrict__ pmax, float* __restrict__ psum) {
    __shared__ float zl[8 * 264];      // [h*264 + row]
    int t = threadIdx.x;
    int b = blockIdx.y;
    int ck = blockIdx.x;
    int n0 = ck << 8;
    int w = t >> 6, lane = t & 63, sub8 = lane >> 3, mq8 = lane & 7;

    // k fragments: lane holds m = mq8*8 .. mq8*8+7 for every h (pre-scaled)
    float4 ka[8], kb[8];
    #pragma unroll
    for (int h = 0; h < 8; ++h) {
        const float* kr = kbuf + (((size_t)b * 8 + h) << 6) + mq8 * 8;
        ka[h] = *(const float4*)(kr);
        kb[h] = *(const float4*)(kr + 4);
    }
    float epsl = P[(((size_t)b * 8 + mq8) << 3)];   // eps/||k|| for head mq8

    const float* mb = mem + ((size_t)b * N_ + n0) * M_;
    #pragma unroll 2
    for (int rr = 0; rr < 8; ++rr) {
        int row = (w << 6) + (rr << 3) + sub8;
        const float* mr = mb + (size_t)row * M_ + mq8 * 8;
        float4 m0 = *(const float4*)(mr);
        float4 m1 = *(const float4*)(mr + 4);
        float pr[9];
        #pragma unroll
        for (int h = 0; h < 8; ++h)
            pr[h] = ka[h].x*m0.x + ka[h].y*m0.y + ka[h].z*m0.z + ka[h].w*m0.w
                  + kb[h].x*m1.x + kb[h].y*m1.y + kb[h].z*m1.z + kb[h].w*m1.w;
        pr[8] = m0.x*m0.x+m0.y*m0.y+m0.z*m0.z+m0.w*m0.w
              + m1.x*m1.x+m1.y*m1.y+m1.z*m1.z+m1.w*m1.w;
        #pragma unroll
        for (int o = 1; o < 8; o <<= 1) {
            #pragma unroll
            for (int i = 0; i < 9; ++i) pr[i] += __shfl_xor(pr[i], o, 64);
        }
        float rn = sqrtf(pr[8]);
        zl[mq8 * 264 + row] = sel8(pr, mq8) / (rn + epsl);
    }
    __syncthreads();

    // z store (coalesced per h)
    #pragma unroll
    for (int h = 0; h < 8; ++h)
        z[(((size_t)b * 8 + h) << 14) + n0 + t] = zl[h * 264 + t];

    // chunk softmax partials: wave w handles h = 2w, 2w+1
    #pragma unroll
    for (int q2 = 0; q2 < 2; ++q2) {
        int h = w * 2 + q2;
        float a0 = zl[h * 264 + lane],       a1 = zl[h * 264 + lane + 64];
        float a2 = zl[h * 264 + lane + 128], a3 = zl[h * 264 + lane + 192];
        float mx = fmaxf(fmaxf(a0, a1), fmaxf(a2, a3));
        #pragma unroll
        for (int o = 32; o > 0; o >>= 1) mx = fmaxf(mx, __shfl_xor(mx, o, 64));
        float se = __expf(a0 - mx) + __expf(a1 - mx) + __expf(a2 - mx) + __expf(a3 - mx);
        #pragma unroll
        for (int o = 32; o > 0; o >>= 1) se += __shfl_xor(se, o, 64);
        if (lane == 0) {
            pmax[(((size_t)b * 8 + h) << 6) + ck] = mx;
            psum[(((size_t)b * 8 + h) << 6) + ck] = se;
        }
    }
}

// ---------------------------------------------------------------------------
// Kernel 4 (pass B): per-block softmax-stats prologue; wg->ws->wp (out_w
// unnormalized); sumwp + readAcc partials. grid (64, 64), block 256.
__global__ __launch_bounds__(256, 4) void k_B(
        const float* __restrict__ mem, const float* __restrict__ z,
        const float* __restrict__ wprev, const float* __restrict__ P,
        const float* __restrict__ pmax, const float* __restrict__ psum,
        float* __restrict__ out_w, float* __restrict__ sumwp,
        float* __restrict__ readAcc) {
    __shared__ float smem[3072 + 2064 + 32 + 64];
    float* wp_s  = smem;               // [row*12 + 0..7]
    float* wgl   = smem + 3072;        // [h*258 + idx] (phase 1)
    float* racc2 = smem + 3072;        // [2048] (phase 2, overlays wgl)
    float* sums  = smem + 5136;        // [32]
    float* pl    = smem + 5168;        // [h*8 + {0:Mx,1:iS,2:g,3:s0,4:s1,5:s2,6:gam}]

    int t = threadIdx.x;
    int b  = blockIdx.y;
    int ck = blockIdx.x;
    int n0 = ck << 8;
    int n = n0 + t;
    int w = t >> 6, lane = t & 63, sub = lane >> 4, mq = lane & 15;

    // prologue: global softmax stats from chunk partials; wave w -> h=2w,2w+1
    #pragma unroll
    for (int q2 = 0; q2 < 2; ++q2) {
        int h = w * 2 + q2;
        size_t bh = (size_t)b * 8 + h;
        float m = pmax[(bh << 6) + lane];
        float s = psum[(bh << 6) + lane];
        float mx = m;
        #pragma unroll
        for (int o = 32; o > 0; o >>= 1) mx = fmaxf(mx, __shfl_xor(mx, o, 64));
        float sc = s * __expf(m - mx);
        #pragma unroll
        for (int o = 32; o > 0; o >>= 1) sc += __shfl_xor(sc, o, 64);
        if (lane == 0) { pl[h * 8 + 0] = mx; pl[h * 8 + 1] = 1.f / sc; }
    }
    if (t < 8) {
        const float* p = P + (((size_t)b * 8 + t) << 3);
        pl[t * 8 + 2] = p[1];
        pl[t * 8 + 3] = p[2];
        pl[t * 8 + 4] = p[3];
        pl[t * 8 + 5] = p[4];
        pl[t * 8 + 6] = p[5];
    }
    __syncthreads();

    // phase 1: wg into LDS (with circular halo)
    #pragma unroll
    for (int h = 0; h < 8; ++h) {
        size_t bh = (size_t)b * 8 + h;
        float Mx = pl[h * 8 + 0], iS = pl[h * 8 + 1], g = pl[h * 8 + 2];
        float wc = __expf(z[(bh << 14) + n] - Mx) * iS;
        wgl[h * 258 + t + 1] = fmaf(g, wc, (1.f - g) * wprev[(bh << 14) + n]);
    }
    if (t < 2) {
        int nh   = (t == 0) ? ((n0 + N_ - 1) & (N_ - 1)) : ((n0 + 256) & (N_ - 1));
        int slot = (t == 0) ? 0 : 257;
        #pragma unroll
        for (int h = 0; h < 8; ++h) {
            size_t bh = (size_t)b * 8 + h;
            float Mx = pl[h * 8 + 0], iS = pl[h * 8 + 1], g = pl[h * 8 + 2];
            float wc = __expf(z[(bh << 14) + nh] - Mx) * iS;
            wgl[h * 258 + slot] = fmaf(g, wc, (1.f - g) * wprev[(bh << 14) + nh]);
        }
    }
    __syncthreads();

    // phase 1b: shift + sharpen -> wp; stage wp; per-wave sums
    float wpv[8];
    #pragma unroll
    for (int h = 0; h < 8; ++h) {
        size_t bh = (size_t)b * 8 + h;
        float s0 = pl[h * 8 + 3], s1 = pl[h * 8 + 4], s2 = pl[h * 8 + 5];
        float gam = pl[h * 8 + 6];
        float wsv = s0 * wgl[h * 258 + t] + s1 * wgl[h * 258 + t + 1]
                  + s2 * wgl[h * 258 + t + 2];
        float v = __powf(wsv, gam);
        wpv[h] = v;
        out_w[(bh << 14) + n] = v;          // unnormalized; k_F rescales
    }
    #pragma unroll
    for (int h = 0; h < 8; ++h) {
        float s = wpv[h];
        #pragma unroll
        for (int o = 32; o > 0; o >>= 1) s += __shfl_down(s, o, 64);
        if (lane == 0) sums[w * 8 + h] = s;
    }
    *(float4*)(wp_s + t * 12)     = make_float4(wpv[0], wpv[1], wpv[2], wpv[3]);
    *(float4*)(wp_s + t * 12 + 4) = make_float4(wpv[4], wpv[5], wpv[6], wpv[7]);
    __syncthreads();

    // phase 2: coalesced weighted read, 16 lanes per row
    float4 acc[8];
    #pragma unroll
    for (int h = 0; h < 8; ++h) acc[h] = make_float4(0.f, 0.f, 0.f, 0.f);
    const float* mb = mem + ((size_t)b * N_ + n0) * M_;
    #pragma unroll
    for (int rr = 0; rr < 16; ++rr) {
        int row = (w << 6) + (rr << 2) + sub;
        float4 mv = *(const float4*)(mb + (size_t)row * M_ + mq * 4);
        float4 wA = *(const float4*)(wp_s + row * 12);
        float4 wB = *(const float4*)(wp_s + row * 12 + 4);
        float wv8[8] = {wA.x, wA.y, wA.z, wA.w, wB.x, wB.y, wB.z, wB.w};
        #pragma unroll
        for (int h = 0; h < 8; ++h) {
            acc[h].x = fmaf(wv8[h], mv.x, acc[h].x);
            acc[h].y = fmaf(wv8[h], mv.y, acc[h].y);
            acc[h].z = fmaf(wv8[h], mv.z, acc[h].z);
            acc[h].w = fmaf(wv8[h], mv.w, acc[h].w);
        }
    }
    #pragma unroll
    for (int h = 0; h < 8; ++h) {
        #pragma unroll
        for (int o = 32; o >= 16; o >>= 1) {
            acc[h].x += __shfl_down(acc[h].x, o, 64);
            acc[h].y += __shfl_down(acc[h].y, o, 64);
            acc[h].z += __shfl_down(acc[h].z, o, 64);
            acc[h].w += __shfl_down(acc[h].w, o, 64);
        }
    }
    if (lane < 16) {
        #pragma unroll
        for (int h = 0; h < 8; ++h)
            *(float4*)(racc2 + ((w * 8 + h) << 6) + mq * 4) = acc[h];
    }
    __syncthreads();
    if (t < 8)
        atomicAdd(&sumwp[b * 8 + t], sums[t] + sums[8 + t] + sums[16 + t] + sums[24 + t]);
    #pragma unroll
    for (int r = 0; r < 2; ++r) {
        int idx = r * 256 + t;
        float s = racc2[idx] + racc2[512 + idx] + racc2[1024 + idx] + racc2[1536 + idx];
        atomicAdd(&readAcc[(size_t)b * 512 + idx], s);
    }
}

// ---------------------------------------------------------------------------
// Kernel 5: normalize w (float4/thread); first 128 blocks also emit read_data.
__global__ void k_F(float* __restrict__ out_w, const float* __restrict__ sumwp,
                    const float* __restrict__ readAcc, float* __restrict__ out_rd) {
    int t = threadIdx.x;
    size_t idx = (size_t)blockIdx.x * 256 + t;   // float4 index
    int bh = (int)(idx >> 12);
    float inv = 1.f / (sumwp[bh] + 1e-16f);
    float4* p = (float4*)out_w + idx;
    float4 v = *p;
    v.x *= inv; v.y *= inv; v.z *= inv; v.w *= inv;
    *p = v;
    if (blockIdx.x < 128) {
        int i = blockIdx.x * 256 + t;            // 32768 total
        out_rd[i] = readAcc[i] / (sumwp[i >> 6] + 1e-16f);
    }
}

// ---------------------------------------------------------------------------
extern "C" void kernel_launch(void* const* d_in, const int* in_sizes, int n_in,
                              void* d_out, int out_size, void* d_ws, size_t ws_size,
                              hipStream_t stream) {
    const float* x     = (const float*)d_in[0];
    const float* mem   = (const float*)d_in[1];
    const float* wprev = (const float*)d_in[2];
    const float* W     = (const float*)d_in[3];
    const float* bias  = (const float*)d_in[4];

    float* out    = (float*)d_out;
    float* out_rd = out;                         // 32768
    float* out_w  = out + 32768;                 // 8388608
    float* out_e  = out + 32768 + 8388608;       // 32768
    float* out_a  = out_e + 32768;               // 32768

    float* ws      = (float*)d_ws;
    float* iv      = ws;                  // 101376  (zeroed)
    float* sumwp   = iv + 101376;         // 512     (zeroed)
    float* readAcc = sumwp + 512;         // 32768   (zeroed)
    float* kbuf    = readAcc + 32768;     // 32768
    float* P       = kbuf + 32768;        // 4096
    float* zbuf    = P + 4096;            // 8388608
    float* pmax    = zbuf + 8388608;      // 32768
    float* psum    = pmax + 32768;        // 32768

    hipMemsetAsync(iv, 0, (size_t)(101376 + 512 + 32768) * 4, stream);

    k_gemm  <<<dim3(25, 4, 8), 64, 0, stream>>>(x, W, iv);
    k_params<<<512, 64, 0, stream>>>(iv, bias, kbuf, P, out_e, out_a);
    k_A     <<<dim3(NCHUNK_, B_), 256, 0, stream>>>(mem, kbuf, P, zbuf, pmax, psum);
    k_B     <<<dim3(NCHUNK_, B_), 256, 0, stream>>>(mem, zbuf, wprev, P, pmax, psum,
                                                    out_w, sumwp, readAcc);
    k_F     <<<8192, 256, 0, stream>>>(out_w, sumwp, readAcc, out_rd);
}

// Round 4
// 530.406 us; speedup vs baseline: 2.0577x; 1.0246x over previous
//
#include <hip/hip_runtime.h>
#include <cstdint>
#include <cstddef>

// Problem constants
#define B_    64
#define H_    8
#define N_    16384
#define M_    64
#define C_    1024
#define IVH_  198          // 3*M+6
#define J_    1584         // H*IVH
#define NCHUNK_ 64         // N/256

__device__ __forceinline__ float softplus_f(float x) {
    return (x > 20.f) ? x : log1pf(__expf(x));
}
__device__ __forceinline__ float sigmoid_f(float x) {
    return 1.f / (1.f + __expf(-x));
}
// branchless 8-way select (cndmask chain; no scratch)
__device__ __forceinline__ float sel8(const float p[8], int i) {
    float r01 = (i & 1) ? p[1] : p[0];
    float r23 = (i & 1) ? p[3] : p[2];
    float r45 = (i & 1) ? p[5] : p[4];
    float r67 = (i & 1) ? p[7] : p[6];
    float a = (i & 2) ? r23 : r01;
    float c = (i & 2) ? r67 : r45;
    return (i & 4) ? c : a;
}

// ---------------------------------------------------------------------------
// Kernel 1: iv = x @ W (no bias; consumers add it). grid (25, 4, 16), block 64.
// 64-c chunks, unroll 8 -> 1600 blocks, 8 W loads in flight.
__global__ __launch_bounds__(64) void k_gemm(const float* __restrict__ x,
                                             const float* __restrict__ W,
                                             float* __restrict__ iv) {
    int lane = threadIdx.x;
    int j = blockIdx.x * 64 + lane;
    bool valid = (j < J_);
    int b0 = blockIdx.y * 16;
    int c0 = blockIdx.z * 64;
    const float* xb = x + (size_t)b0 * C_;
    float acc[16];
    #pragma unroll
    for (int i = 0; i < 16; ++i) acc[i] = 0.f;
    #pragma unroll 8
    for (int c = c0; c < c0 + 64; ++c) {
        float wv = valid ? W[(size_t)c * J_ + j] : 0.f;
        #pragma unroll
        for (int bi = 0; bi < 16; ++bi)
            acc[bi] = fmaf(xb[(size_t)bi * C_ + c], wv, acc[bi]);
    }
    if (valid) {
        #pragma unroll
        for (int bi = 0; bi < 16; ++bi)
            atomicAdd(&iv[(size_t)(b0 + bi) * J_ + j], acc[bi]);
    }
}

// ---------------------------------------------------------------------------
// Kernel 2: per-(b,h) parameter extraction. grid 512 blocks, block 64.
// kbuf = k * beta/||k||; P = {eps/||k||, beta, g, s0, s1, s2, gamma};
// e/a epilogue outputs emitted here.
__global__ void k_params(const float* __restrict__ iv, const float* __restrict__ bias,
                         float* __restrict__ kbuf, float* __restrict__ P,
                         float* __restrict__ out_e, float* __restrict__ out_a) {
    int bh = blockIdx.x;
    int m  = threadIdx.x;              // 0..63
    int b = bh >> 3, h = bh & 7;
    const float* row = iv + (size_t)b * J_ + h * IVH_;
    const float* bb  = bias + h * IVH_;
    float kv = row[m] + bb[m];
    float s = kv * kv;
    #pragma unroll
    for (int o = 32; o > 0; o >>= 1) s += __shfl_xor(s, o, 64);
    float kn = sqrtf(s);
    float beta = softplus_f(row[64] + bb[64]);     // wave-uniform loads
    kbuf[(size_t)bh * 64 + m] = kv * (beta / kn);  // beta/||k|| folded into k
    float ev = row[70 + m] + bb[70 + m];           // M+6 = 70
    out_e[(size_t)bh * 64 + m] = sigmoid_f(ev);
    out_a[(size_t)bh * 64 + m] = row[134 + m] + bb[134 + m];  // 2M+6 = 134
    if (m == 0) {
        float v1 = row[65] + bb[65];
        float v2 = row[66] + bb[66];
        float v3 = row[67] + bb[67];
        float v4 = row[68] + bb[68];
        float v5 = row[69] + bb[69];
        float mx3 = fmaxf(v2, fmaxf(v3, v4));
        float e2 = __expf(v2 - mx3), e3 = __expf(v3 - mx3), e4 = __expf(v4 - mx3);
        float inv = 1.f / (e2 + e3 + e4);
        float* p = P + (size_t)bh * 8;
        p[0] = 1e-16f / kn;            // beta*dot/(kn*rn+eps) == khat.dot/(rn+eps/kn)
        p[1] = beta;
        p[2] = sigmoid_f(v1);          // g
        p[3] = e2 * inv; p[4] = e3 * inv; p[5] = e4 * inv;  // s0,s1,s2
        p[6] = 1.f + softplus_f(v5);   // gamma
    }
}

// ---------------------------------------------------------------------------
// Kernel 3 (pass A): u = exp(beta*(cos-1)) for one 256-row chunk (beta is a
// safe stabilizer since beta*cos <= beta -> no max pass needed); per-chunk
// sum partials only. 8 lanes per row, 3-stage xor reduce, fully unrolled rr
// loop for load MLP. grid (64, 64), block 256.
__global__ __launch_bounds__(256, 3) void k_A(
        const float* __restrict__ mem, const float* __restrict__ kbuf,
        const float* __restrict__ P, float* __restrict__ u,
        float* __restrict__ psum) {
    __shared__ float zl[8 * 264];      // [h*264 + row], now holds u
    int t = threadIdx.x;
    int b = blockIdx.y;
    int ck = blockIdx.x;
    int n0 = ck << 8;
    int w = t >> 6, lane = t & 63, sub8 = lane >> 3, mq8 = lane & 7;

    // k fragments: lane holds m = mq8*8 .. mq8*8+7 for every h (pre-scaled)
    float4 ka[8], kb[8];
    #pragma unroll
    for (int h = 0; h < 8; ++h) {
        const float* kr = kbuf + (((size_t)b * 8 + h) << 6) + mq8 * 8;
        ka[h] = *(const float4*)(kr);
        kb[h] = *(const float4*)(kr + 4);
    }
    const float* pp = P + (((size_t)b * 8 + mq8) << 3);
    float epsl = pp[0];                // eps/||k|| for head mq8
    float beta = pp[1];                // stabilizer for head mq8

    const float* mb = mem + ((size_t)b * N_ + n0) * M_;
    #pragma unroll
    for (int rr = 0; rr < 8; ++rr) {
        int row = (w << 6) + (rr << 3) + sub8;
        const float* mr = mb + (size_t)row * M_ + mq8 * 8;
        float4 m0 = *(const float4*)(mr);
        float4 m1 = *(const float4*)(mr + 4);
        float pr[9];
        #pragma unroll
        for (int h = 0; h < 8; ++h)
            pr[h] = ka[h].x*m0.x + ka[h].y*m0.y + ka[h].z*m0.z + ka[h].w*m0.w
                  + kb[h].x*m1.x + kb[h].y*m1.y + kb[h].z*m1.z + kb[h].w*m1.w;
        pr[8] = m0.x*m0.x+m0.y*m0.y+m0.z*m0.z+m0.w*m0.w
              + m1.x*m1.x+m1.y*m1.y+m1.z*m1.z+m1.w*m1.w;
        #pragma unroll
        for (int o = 1; o < 8; o <<= 1) {
            #pragma unroll
            for (int i = 0; i < 9; ++i) pr[i] += __shfl_xor(pr[i], o, 64);
        }
        float rn = sqrtf(pr[8]);
        float q = sel8(pr, mq8) / (rn + epsl);     // beta*cos
        zl[mq8 * 264 + row] = __expf(q - beta);    // u in (0,1]
    }
    __syncthreads();

    // u store (coalesced per h)
    #pragma unroll
    for (int h = 0; h < 8; ++h)
        u[(((size_t)b * 8 + h) << 14) + n0 + t] = zl[h * 264 + t];

    // chunk sum partials: wave w handles h = 2w, 2w+1
    #pragma unroll
    for (int q2 = 0; q2 < 2; ++q2) {
        int h = w * 2 + q2;
        float se = zl[h * 264 + lane]       + zl[h * 264 + lane + 64]
                 + zl[h * 264 + lane + 128] + zl[h * 264 + lane + 192];
        #pragma unroll
        for (int o = 32; o > 0; o >>= 1) se += __shfl_xor(se, o, 64);
        if (lane == 0)
            psum[(((size_t)b * 8 + h) << 6) + ck] = se;
    }
}

// ---------------------------------------------------------------------------
// Kernel 4: reduce chunk sums -> per-(b,h) combined constants
// C = {A1 = g/S, A2 = 1-g, s0, s1, s2, gamma}. grid 128, block 256.
__global__ void k_stats(const float* __restrict__ psum, const float* __restrict__ P,
                        float* __restrict__ C) {
    int bh = blockIdx.x * 4 + (threadIdx.x >> 6);
    int lane = threadIdx.x & 63;
    float s = psum[((size_t)bh << 6) + lane];
    #pragma unroll
    for (int o = 32; o > 0; o >>= 1) s += __shfl_xor(s, o, 64);
    if (lane == 0) {
        const float* p = P + (size_t)bh * 8;
        float g = p[2];
        float iS = 1.f / s;
        float* c = C + (size_t)bh * 8;
        c[0] = g * iS;     // A1
        c[1] = 1.f - g;    // A2
        c[2] = p[3]; c[3] = p[4]; c[4] = p[5]; c[5] = p[6];
    }
}

// ---------------------------------------------------------------------------
// Kernel 5 (pass B): wg = A1*u + A2*wprev (one fma, no exp, no prologue
// reduce); shift+sharpen -> wp (out_w unnormalized); sumwp + readAcc
// partials. Reversed traversal for LLC tail reuse. grid (64, 64), block 256.
__global__ __launch_bounds__(256, 4) void k_B(
        const float* __restrict__ mem, const float* __restrict__ u,
        const float* __restrict__ wprev, const float* __restrict__ C,
        float* __restrict__ out_w, float* __restrict__ sumwp,
        float* __restrict__ readAcc) {
    __shared__ float smem[3072 + 2064 + 32 + 64];
    float* wp_s  = smem;               // [row*12 + 0..7]
    float* wgl   = smem + 3072;        // [h*258 + idx] (phase 1)
    float* racc2 = smem + 3072;        // [2048] (phase 2, overlays wgl)
    float* sums  = smem + 5136;        // [32]
    float* pl    = smem + 5168;        // [h*8 + {0:A1,1:A2,2:s0,3:s1,4:s2,5:gam}]

    int t = threadIdx.x;
    int b  = (B_ - 1) - blockIdx.y;        // reversed
    int ck = (NCHUNK_ - 1) - blockIdx.x;   // reversed
    int n0 = ck << 8;
    int n = n0 + t;
    int w = t >> 6, lane = t & 63, sub = lane >> 4, mq = lane & 15;

    if (t < 48) {                      // 8 heads x 6 consts
        int h = t / 6, i = t - h * 6;
        pl[h * 8 + i] = C[(((size_t)b * 8 + h) << 3) + i];
    }
    __syncthreads();

    // phase 1: wg into LDS (with circular halo)
    #pragma unroll
    for (int h = 0; h < 8; ++h) {
        size_t bh = (size_t)b * 8 + h;
        float A1 = pl[h * 8 + 0], A2 = pl[h * 8 + 1];
        wgl[h * 258 + t + 1] = fmaf(A1, u[(bh << 14) + n], A2 * wprev[(bh << 14) + n]);
    }
    if (t < 2) {
        int nh   = (t == 0) ? ((n0 + N_ - 1) & (N_ - 1)) : ((n0 + 256) & (N_ - 1));
        int slot = (t == 0) ? 0 : 257;
        #pragma unroll
        for (int h = 0; h < 8; ++h) {
            size_t bh = (size_t)b * 8 + h;
            float A1 = pl[h * 8 + 0], A2 = pl[h * 8 + 1];
            wgl[h * 258 + slot] = fmaf(A1, u[(bh << 14) + nh], A2 * wprev[(bh << 14) + nh]);
        }
    }
    __syncthreads();

    // phase 1b: shift + sharpen -> wp; stage wp; per-wave sums
    float wpv[8];
    #pragma unroll
    for (int h = 0; h < 8; ++h) {
        size_t bh = (size_t)b * 8 + h;
        float s0 = pl[h * 8 + 2], s1 = pl[h * 8 + 3], s2 = pl[h * 8 + 4];
        float gam = pl[h * 8 + 5];
        float wsv = s0 * wgl[h * 258 + t] + s1 * wgl[h * 258 + t + 1]
                  + s2 * wgl[h * 258 + t + 2];
        float v = __powf(wsv, gam);
        wpv[h] = v;
        out_w[(bh << 14) + n] = v;          // unnormalized; k_F rescales
    }
    #pragma unroll
    for (int h = 0; h < 8; ++h) {
        float s = wpv[h];
        #pragma unroll
        for (int o = 32; o > 0; o >>= 1) s += __shfl_down(s, o, 64);
        if (lane == 0) sums[w * 8 + h] = s;
    }
    *(float4*)(wp_s + t * 12)     = make_float4(wpv[0], wpv[1], wpv[2], wpv[3]);
    *(float4*)(wp_s + t * 12 + 4) = make_float4(wpv[4], wpv[5], wpv[6], wpv[7]);
    __syncthreads();

    // phase 2: coalesced weighted read, 16 lanes per row, unroll 4 for MLP
    float4 acc[8];
    #pragma unroll
    for (int h = 0; h < 8; ++h) acc[h] = make_float4(0.f, 0.f, 0.f, 0.f);
    const float* mb = mem + ((size_t)b * N_ + n0) * M_;
    #pragma unroll 4
    for (int rr = 0; rr < 16; ++rr) {
        int row = (w << 6) + (rr << 2) + sub;
        float4 mv = *(const float4*)(mb + (size_t)row * M_ + mq * 4);
        float4 wA = *(const float4*)(wp_s + row * 12);
        float4 wB = *(const float4*)(wp_s + row * 12 + 4);
        float wv8[8] = {wA.x, wA.y, wA.z, wA.w, wB.x, wB.y, wB.z, wB.w};
        #pragma unroll
        for (int h = 0; h < 8; ++h) {
            acc[h].x = fmaf(wv8[h], mv.x, acc[h].x);
            acc[h].y = fmaf(wv8[h], mv.y, acc[h].y);
            acc[h].z = fmaf(wv8[h], mv.z, acc[h].z);
            acc[h].w = fmaf(wv8[h], mv.w, acc[h].w);
        }
    }
    #pragma unroll
    for (int h = 0; h < 8; ++h) {
        #pragma unroll
        for (int o = 32; o >= 16; o >>= 1) {
            acc[h].x += __shfl_down(acc[h].x, o, 64);
            acc[h].y += __shfl_down(acc[h].y, o, 64);
            acc[h].z += __shfl_down(acc[h].z, o, 64);
            acc[h].w += __shfl_down(acc[h].w, o, 64);
        }
    }
    if (lane < 16) {
        #pragma unroll
        for (int h = 0; h < 8; ++h)
            *(float4*)(racc2 + ((w * 8 + h) << 6) + mq * 4) = acc[h];
    }
    __syncthreads();
    if (t < 8)
        atomicAdd(&sumwp[b * 8 + t], sums[t] + sums[8 + t] + sums[16 + t] + sums[24 + t]);
    #pragma unroll
    for (int r = 0; r < 2; ++r) {
        int idx = r * 256 + t;
        float s = racc2[idx] + racc2[512 + idx] + racc2[1024 + idx] + racc2[1536 + idx];
        atomicAdd(&readAcc[(size_t)b * 512 + idx], s);
    }
}

// ---------------------------------------------------------------------------
// Kernel 6: normalize w (float4/thread); first 128 blocks also emit read_data.
__global__ void k_F(float* __restrict__ out_w, const float* __restrict__ sumwp,
                    const float* __restrict__ readAcc, float* __restrict__ out_rd) {
    int t = threadIdx.x;
    size_t idx = (size_t)blockIdx.x * 256 + t;   // float4 index
    int bh = (int)(idx >> 12);
    float inv = 1.f / (sumwp[bh] + 1e-16f);
    float4* p = (float4*)out_w + idx;
    float4 v = *p;
    v.x *= inv; v.y *= inv; v.z *= inv; v.w *= inv;
    *p = v;
    if (blockIdx.x < 128) {
        int i = blockIdx.x * 256 + t;            // 32768 total
        out_rd[i] = readAcc[i] / (sumwp[i >> 6] + 1e-16f);
    }
}

// ---------------------------------------------------------------------------
extern "C" void kernel_launch(void* const* d_in, const int* in_sizes, int n_in,
                              void* d_out, int out_size, void* d_ws, size_t ws_size,
                              hipStream_t stream) {
    const float* x     = (const float*)d_in[0];
    const float* mem   = (const float*)d_in[1];
    const float* wprev = (const float*)d_in[2];
    const float* W     = (const float*)d_in[3];
    const float* bias  = (const float*)d_in[4];

    float* out    = (float*)d_out;
    float* out_rd = out;                         // 32768
    float* out_w  = out + 32768;                 // 8388608
    float* out_e  = out + 32768 + 8388608;       // 32768
    float* out_a  = out_e + 32768;               // 32768

    float* ws      = (float*)d_ws;
    float* iv      = ws;                  // 101376  (zeroed)
    float* sumwp   = iv + 101376;         // 512     (zeroed)
    float* readAcc = sumwp + 512;         // 32768   (zeroed)
    float* kbuf    = readAcc + 32768;     // 32768
    float* P       = kbuf + 32768;        // 4096
    float* Cb      = P + 4096;            // 4096
    float* ubuf    = Cb + 4096;           // 8388608
    float* psum    = ubuf + 8388608;      // 32768

    hipMemsetAsync(iv, 0, (size_t)(101376 + 512 + 32768) * 4, stream);

    k_gemm  <<<dim3(25, 4, 16), 64, 0, stream>>>(x, W, iv);
    k_params<<<512, 64, 0, stream>>>(iv, bias, kbuf, P, out_e, out_a);
    k_A     <<<dim3(NCHUNK_, B_), 256, 0, stream>>>(mem, kbuf, P, ubuf, psum);
    k_stats <<<128, 256, 0, stream>>>(psum, P, Cb);
    k_B     <<<dim3(NCHUNK_, B_), 256, 0, stream>>>(mem, ubuf, wprev, Cb,
                                                    out_w, sumwp, readAcc);
    k_F     <<<8192, 256, 0, stream>>>(out_w, sumwp, readAcc, out_rd);
}